// Round 8
// baseline (227.099 us; speedup 1.0000x reference)
//
#include <hip/hip_runtime.h>
#include <hip/hip_bf16.h>

// Problem constants: B=2, T=2048, C=1024, H=16, D=64
#define B_ 2
#define T_ 2048
#define C_ 1024
#define H_ 16
#define D_ 64
#define M_ 4096
#define N3C 3072

using short8  = __attribute__((ext_vector_type(8))) short;
using floatx4 = __attribute__((ext_vector_type(4))) float;
typedef unsigned int u32;

__device__ __forceinline__ unsigned short f2b(float f) {
  __hip_bfloat16 h = __float2bfloat16(f);
  return *reinterpret_cast<unsigned short*>(&h);
}
__device__ __forceinline__ float b2f(unsigned short u) {
  union { unsigned int i; float f; } x; x.i = ((unsigned int)u) << 16; return x.f;
}

// async global->LDS, 16B per lane; LDS dest = wave-uniform base + lane*16
__device__ __forceinline__ void gll16(const void* g, void* l) {
  __builtin_amdgcn_global_load_lds((const __attribute__((address_space(1))) u32*)g,
                                   (__attribute__((address_space(3))) u32*)l, 16, 0, 0);
}

// ---------------- ternarization ----------------

// both tensors in one launch; per-block LDS reduce -> 1 atomic/block
__global__ void abs_sum2(const float* __restrict__ wq, const float* __restrict__ wp,
                         double* __restrict__ sums) {
  __shared__ double red[4];
  const float* w = blockIdx.y ? wp : wq;
  const int n4 = blockIdx.y ? (C_ * C_ / 4) : (3 * C_ * C_ / 4);
  int stride = gridDim.x * blockDim.x;
  double s = 0.0;
  for (int i = blockIdx.x * blockDim.x + threadIdx.x; i < n4; i += stride) {
    float4 v = ((const float4*)w)[i];
    s += (double)fabsf(v.x) + (double)fabsf(v.y) + (double)fabsf(v.z) + (double)fabsf(v.w);
  }
  #pragma unroll
  for (int off = 32; off > 0; off >>= 1)
    s += __shfl_down(s, off, 64);
  if ((threadIdx.x & 63) == 0) red[threadIdx.x >> 6] = s;
  __syncthreads();
  if (threadIdx.x == 0) atomicAdd(sums + blockIdx.y, (red[0] + red[1]) + (red[2] + red[3]));
}

// ternarize both weight tensors (exact {-1,0,+1} bf16) + cvt x->bf16, one launch
__global__ void tern_cvt(const float* __restrict__ wq, const float* __restrict__ wp,
                         const float* __restrict__ x,
                         unsigned short* __restrict__ oq, unsigned short* __restrict__ op,
                         unsigned short* __restrict__ xb,
                         const double* __restrict__ sums, float* __restrict__ ams) {
  const int NQ = 3 * C_ * C_;
  const int NP = C_ * C_;
  int i = blockIdx.x * blockDim.x + threadIdx.x;
  float am0 = fmaxf((float)(sums[0] * (1.0 / NQ)), 1e-5f);
  float am1 = fmaxf((float)(sums[1] * (1.0 / NP)), 1e-5f);
  if (i == 0) { ams[0] = am0; ams[1] = am1; }
  if (i < NQ) {
    float thr = 0.7f * am0, v = wq[i];
    oq[i] = (v > thr) ? 0x3F80u : ((v < -thr) ? 0xBF80u : 0u);
  } else if (i < NQ + NP) {
    int j = i - NQ;
    float thr = 0.7f * am1, v = wp[j];
    op[j] = (v > thr) ? 0x3F80u : ((v < -thr) ? 0xBF80u : 0u);
  } else {
    int j = i - NQ - NP;                       // 0 .. M_*C_/4-1
    float4 v = ((const float4*)x)[j];
    ushort4 o; o.x = f2b(v.x); o.y = f2b(v.y); o.z = f2b(v.z); o.w = f2b(v.w);
    ((ushort4*)xb)[j] = o;
  }
}

// ---------------- QKV GEMM with fused RoPE/head-split/V-transpose epilogue ----
// 128x128 tile, BK=32, 256 threads, global_load_lds staging. Epilogue:
// q/k -> in-register RoPE (partners acc[r][c]/acc[r][c^2]) -> Qb/Kb [bh][t][d];
// v -> Vtb [bh][d][t] DIRECTLY (transpose fused; L2 write-combining keeps HBM
// traffic at 8 MB). Q pre-scaled by am*0.125*log2e.

__global__ __launch_bounds__(256) void gemm_qkv(const unsigned short* __restrict__ A,
                                                const unsigned short* __restrict__ W,
                                                const float* __restrict__ scale_ptr,
                                                const float* __restrict__ cosp,
                                                const float* __restrict__ sinp,
                                                unsigned short* __restrict__ Qb,
                                                unsigned short* __restrict__ Kb,
                                                unsigned short* __restrict__ Vtb) {
  const int K = C_;
  __shared__ __attribute__((aligned(16))) unsigned short As[128 * 32];
  __shared__ __attribute__((aligned(16))) unsigned short Ws[128 * 32];
  const int tid = threadIdx.x, lane = tid & 63, wv = tid >> 6;
  const int m = lane & 15, g = lane >> 4;
  const int m0 = blockIdx.y * 128, n0 = blockIdx.x * 128;
  const int wm = (wv >> 1) * 64, wn = (wv & 1) * 64;

  const int srow = wv * 16 + (lane >> 2);
  const int skoff = (lane & 3) * 8;
  const unsigned short* ga0 = A + (size_t)(m0 + srow) * K + skoff;
  const unsigned short* ga1 = A + (size_t)(m0 + 64 + srow) * K + skoff;
  const unsigned short* gw0 = W + (size_t)(n0 + srow) * K + skoff;
  const unsigned short* gw1 = W + (size_t)(n0 + 64 + srow) * K + skoff;
  unsigned short* la0 = As + (wv * 16) * 32;
  unsigned short* la1 = As + (64 + wv * 16) * 32;
  unsigned short* lw0 = Ws + (wv * 16) * 32;
  unsigned short* lw1 = Ws + (64 + wv * 16) * 32;

  floatx4 acc[4][4] = {};
  for (int kc = 0; kc < K; kc += 32) {
    __syncthreads();
    gll16(ga0, la0); gll16(ga1, la1); gll16(gw0, lw0); gll16(gw1, lw1);
    ga0 += 32; ga1 += 32; gw0 += 32; gw1 += 32;
    __syncthreads();
    short8 af[4], wf[4];
    #pragma unroll
    for (int r = 0; r < 4; r++)
      af[r] = *(const short8*)&As[(wm + r * 16 + m) * 32 + g * 8];
    #pragma unroll
    for (int c = 0; c < 4; c++)
      wf[c] = *(const short8*)&Ws[(wn + c * 16 + m) * 32 + g * 8];
    #pragma unroll
    for (int r = 0; r < 4; r++)
      #pragma unroll
      for (int c = 0; c < 4; c++)
        acc[r][c] = __builtin_amdgcn_mfma_f32_16x16x32_bf16(af[r], wf[c], acc[r][c], 0, 0, 0);
  }

  const float am = *scale_ptr;
  const int sect = n0 >> 10;            // 0=q, 1=k, 2=v (block-uniform)
  const int nloc = n0 & 1023;
  const int h = (nloc + wn) >> 6;       // head for this wave's 64-col half
  if (sect < 2) {
    unsigned short* dst = sect ? Kb : Qb;
    const float sc = sect ? am : am * 0.18033688011112042f;  // am * 0.125 * log2(e)
    #pragma unroll
    for (int r = 0; r < 4; r++)
      #pragma unroll
      for (int i = 0; i < 4; i++) {
        int row = m0 + wm + r * 16 + g * 4 + i;
        int t = row & (T_ - 1), b = row >> 11;
        size_t obase = ((size_t)(b * H_ + h) * T_ + t) * 64;
        #pragma unroll
        for (int c = 0; c < 4; c++) {
          int p = c * 16 + m;
          float cv = cosp[t * 64 + p], sv = sinp[t * 64 + p];
          float a = acc[r][c][i], pt = acc[r][c ^ 2][i];
          float val = (c < 2) ? (a * cv - pt * sv) : (a * cv + pt * sv);
          dst[obase + p] = f2b(val * sc);
        }
      }
  } else {
    #pragma unroll
    for (int r = 0; r < 4; r++)
      #pragma unroll
      for (int i = 0; i < 4; i++) {
        int row = m0 + wm + r * 16 + g * 4 + i;
        int t = row & (T_ - 1), b = row >> 11;
        size_t hbase = (size_t)(b * H_ + h) * 64 * T_;
        #pragma unroll
        for (int c = 0; c < 4; c++)
          Vtb[hbase + (size_t)(c * 16 + m) * T_ + t] = f2b(acc[r][c][i] * am);
      }
  }
}

// ---------------- plain MFMA GEMM (proj): out[M,N] = (A @ W^T) * scale ------

__global__ __launch_bounds__(256) void gemm128(const unsigned short* __restrict__ A,
                                               const unsigned short* __restrict__ W,
                                               const float* __restrict__ scale_ptr,
                                               float* __restrict__ Cout,
                                               int N, int K) {
  __shared__ __attribute__((aligned(16))) unsigned short As[128 * 32];
  __shared__ __attribute__((aligned(16))) unsigned short Ws[128 * 32];
  const int tid = threadIdx.x, lane = tid & 63, wv = tid >> 6;
  const int m = lane & 15, g = lane >> 4;
  const int m0 = blockIdx.y * 128, n0 = blockIdx.x * 128;
  const int wm = (wv >> 1) * 64, wn = (wv & 1) * 64;

  const int srow = wv * 16 + (lane >> 2);
  const int skoff = (lane & 3) * 8;
  const unsigned short* ga0 = A + (size_t)(m0 + srow) * K + skoff;
  const unsigned short* ga1 = A + (size_t)(m0 + 64 + srow) * K + skoff;
  const unsigned short* gw0 = W + (size_t)(n0 + srow) * K + skoff;
  const unsigned short* gw1 = W + (size_t)(n0 + 64 + srow) * K + skoff;
  unsigned short* la0 = As + (wv * 16) * 32;
  unsigned short* la1 = As + (64 + wv * 16) * 32;
  unsigned short* lw0 = Ws + (wv * 16) * 32;
  unsigned short* lw1 = Ws + (64 + wv * 16) * 32;

  floatx4 acc[4][4] = {};
  for (int kc = 0; kc < K; kc += 32) {
    __syncthreads();
    gll16(ga0, la0); gll16(ga1, la1); gll16(gw0, lw0); gll16(gw1, lw1);
    ga0 += 32; ga1 += 32; gw0 += 32; gw1 += 32;
    __syncthreads();
    short8 af[4], wf[4];
    #pragma unroll
    for (int r = 0; r < 4; r++)
      af[r] = *(const short8*)&As[(wm + r * 16 + m) * 32 + g * 8];
    #pragma unroll
    for (int c = 0; c < 4; c++)
      wf[c] = *(const short8*)&Ws[(wn + c * 16 + m) * 32 + g * 8];
    #pragma unroll
    for (int r = 0; r < 4; r++)
      #pragma unroll
      for (int c = 0; c < 4; c++)
        acc[r][c] = __builtin_amdgcn_mfma_f32_16x16x32_bf16(af[r], wf[c], acc[r][c], 0, 0, 0);
  }

  const float scale = *scale_ptr;
  #pragma unroll
  for (int r = 0; r < 4; r++)
    #pragma unroll
    for (int c = 0; c < 4; c++)
      #pragma unroll
      for (int i = 0; i < 4; i++) {
        int row = m0 + wm + r * 16 + g * 4 + i;
        int col = n0 + wn + c * 16 + m;
        Cout[(size_t)row * N + col] = acc[r][c][i] * scale;
      }
}

// ---------------- MFMA flash attention, m=0 softmax, LDS-staged K/V ----------
// 512 blocks, one 128-q strip each (16 strips x 32 bh). gid->(bh,s) with XCD
// locality (4 bh per gid%8) and long strips dispatched first (LPT balance at
// 2 blocks/CU). Block = 4 waves; wave owns 32 q (2 accumulator sets, shared
// K-fragment reads). K/V double-buffered via global_load_lds, XOR-swizzled
// 16B chunks. S^T = K*Q^T; P via per-wave LDS round-trip; O += P*V.

__global__ __launch_bounds__(256) void flash_mfma(const unsigned short* __restrict__ Qb,
                                                  const unsigned short* __restrict__ Kb,
                                                  const unsigned short* __restrict__ Vtb,
                                                  unsigned short* __restrict__ Y) {
  __shared__ __align__(16) unsigned short Ktile[2][64][64];   // [buf][t][d]
  __shared__ __align__(16) unsigned short Vtile[2][64][64];   // [buf][d][t]
  __shared__ __align__(16) unsigned short Plds[4][16][72];
  const int lane = threadIdx.x & 63;
  const int wv = threadIdx.x >> 6;
  const int m = lane & 15, g = lane >> 4;
  const int gid = blockIdx.x;
  const int xcd = gid & 7, j = gid >> 3;    // j: 0..63
  const int bh = xcd * 4 + (j & 3);
  const int s = 15 - (j >> 2);              // long strips dispatched first
  const int b = bh >> 4, h = bh & 15;
  const size_t hb = (size_t)bh * T_ * 64;
  const unsigned short* Kbh = Kb + hb;
  const unsigned short* Vbh = Vtb + hb;     // [64][T_]
  const int r8 = lane >> 3, cc8 = lane & 7;
  const int gcol = ((cc8 ^ r8) << 3);       // swizzled global chunk

  const int ntiles = 2 * s + 2;
  const int qb0 = s * 128 + wv * 32;        // qset0 base (16 rows)
  const int qb1 = qb0 + 16;                 // qset1 base

  const unsigned short* qp0 = Qb + hb + (size_t)(qb0 + m) * 64 + g * 8;
  short8 qf00 = *(const short8*)qp0;
  short8 qf01 = *(const short8*)(qp0 + 32);
  const unsigned short* qp1 = qp0 + 16 * 64;
  short8 qf10 = *(const short8*)qp1;
  short8 qf11 = *(const short8*)(qp1 + 32);

  floatx4 O0[4] = {}, O1[4] = {};
  float ls0 = 0.f, ls1 = 0.f;

  #pragma unroll
  for (int cc = 0; cc < 2; cc++) {          // stage tile 0 -> buf 0
    int row = wv * 16 + cc * 8;
    gll16(Kbh + (size_t)(row + r8) * 64 + gcol, &Ktile[0][row][0]);
    gll16(Vbh + (size_t)(row + r8) * T_ + gcol, &Vtile[0][row][0]);
  }

  for (int kt = 0; kt < ntiles; kt++) {
    const int buf = kt & 1;
    const int kb = kt * 64;
    __syncthreads();                         // stage(kt) visible
    if (kt + 1 < ntiles) {                   // stream next tile
      const int kb2 = kb + 64;
      #pragma unroll
      for (int cc = 0; cc < 2; cc++) {
        int row = wv * 16 + cc * 8;
        gll16(Kbh + (size_t)(kb2 + row + r8) * 64 + gcol, &Ktile[1 - buf][row][0]);
        gll16(Vbh + (size_t)(row + r8) * T_ + kb2 + gcol, &Vtile[1 - buf][row][0]);
      }
    }
    if (kb > qb0 + 31) continue;             // whole wave past causal frontier

    auto do_qset = [&](short8 qa, short8 qb_, int qbase, float& lsum, floatx4* O) {
      floatx4 S[4];
      #pragma unroll
      for (int mt = 0; mt < 4; mt++) {
        int row = mt * 16 + m;
        short8 kf0 = *(const short8*)&Ktile[buf][row][(g ^ (m & 7)) << 3];
        short8 kf1 = *(const short8*)&Ktile[buf][row][((g + 4) ^ (m & 7)) << 3];
        floatx4 sv = {};
        sv = __builtin_amdgcn_mfma_f32_16x16x32_bf16(kf0, qa, sv, 0, 0, 0);
        sv = __builtin_amdgcn_mfma_f32_16x16x32_bf16(kf1, qb_, sv, 0, 0, 0);
        S[mt] = sv;
      }
      if (kb + 64 <= qbase) {                // fully unmasked tile
        #pragma unroll
        for (int mt = 0; mt < 4; mt++) {
          float e0 = exp2f(S[mt][0]), e1 = exp2f(S[mt][1]);
          float e2 = exp2f(S[mt][2]), e3 = exp2f(S[mt][3]);
          lsum += (e0 + e1) + (e2 + e3);
          ushort4 o; o.x = f2b(e0); o.y = f2b(e1); o.z = f2b(e2); o.w = f2b(e3);
          *(ushort4*)&Plds[wv][m][mt * 16 + g * 4] = o;
        }
      } else {                               // diagonal zone: causal mask
        const int q_glob = qbase + m;
        #pragma unroll
        for (int mt = 0; mt < 4; mt++) {
          float e[4];
          #pragma unroll
          for (int r = 0; r < 4; r++) {
            int kg = kb + mt * 16 + g * 4 + r;
            e[r] = (kg <= q_glob) ? exp2f(S[mt][r]) : 0.f;
          }
          lsum += (e[0] + e[1]) + (e[2] + e[3]);
          ushort4 o; o.x = f2b(e[0]); o.y = f2b(e[1]); o.z = f2b(e[2]); o.w = f2b(e[3]);
          *(ushort4*)&Plds[wv][m][mt * 16 + g * 4] = o;
        }
      }
      short8 pa0 = *(const short8*)&Plds[wv][m][g * 8];
      short8 pa1 = *(const short8*)&Plds[wv][m][32 + g * 8];
      #pragma unroll
      for (int nt = 0; nt < 4; nt++) {
        int row = nt * 16 + m;
        short8 v0 = *(const short8*)&Vtile[buf][row][(g ^ (m & 7)) << 3];
        short8 v1 = *(const short8*)&Vtile[buf][row][((g + 4) ^ (m & 7)) << 3];
        O[nt] = __builtin_amdgcn_mfma_f32_16x16x32_bf16(pa0, v0, O[nt], 0, 0, 0);
        O[nt] = __builtin_amdgcn_mfma_f32_16x16x32_bf16(pa1, v1, O[nt], 0, 0, 0);
      }
    };

    do_qset(qf00, qf01, qb0, ls0, O0);                       // qset0
    if (kb <= qb1 + 15) do_qset(qf10, qf11, qb1, ls1, O1);   // qset1
  }

  // per-qset: reduce l across g-lanes sharing q=m, normalize, store
  #pragma unroll
  for (int jq = 0; jq < 2; jq++) {
    float lsum = jq ? ls1 : ls0;
    floatx4* O = jq ? O1 : O0;
    const int qbase = jq ? qb1 : qb0;
    lsum += __shfl_xor(lsum, 16, 64);
    lsum += __shfl_xor(lsum, 32, 64);
    float li[4];
    #pragma unroll
    for (int r = 0; r < 4; r++) li[r] = 1.0f / __shfl(lsum, g * 4 + r, 64);
    #pragma unroll
    for (int nt = 0; nt < 4; nt++)
      #pragma unroll
      for (int r = 0; r < 4; r++) {
        int trow = qbase + g * 4 + r;
        int col = h * 64 + nt * 16 + m;
        Y[(size_t)(b * T_ + trow) * C_ + col] = f2b(O[nt][r] * li[r]);
      }
  }
}

// ---------------- launch ----------------

extern "C" void kernel_launch(void* const* d_in, const int* in_sizes, int n_in,
                              void* d_out, int out_size, void* d_ws, size_t ws_size,
                              hipStream_t stream) {
  (void)in_sizes; (void)n_in; (void)out_size; (void)ws_size;
  const float* x      = (const float*)d_in[0];
  const float* cosp   = (const float*)d_in[1];
  const float* sinp   = (const float*)d_in[2];
  const float* w_qkv  = (const float*)d_in[3];
  const float* w_proj = (const float*)d_in[4];
  float* out = (float*)d_out;

  char* ws = (char*)d_ws;
  double* sums = (double*)ws;                       // 16 B
  float*  ams  = (float*)(ws + 16);                 // 8 B
  unsigned short* wqkv_b  = (unsigned short*)(ws + 256);            // 6 MB
  unsigned short* wproj_b = wqkv_b + (size_t)N3C * C_;              // 2 MB
  unsigned short* xb      = wproj_b + (size_t)C_ * C_;              // 8 MB
  unsigned short* Qb      = xb + (size_t)M_ * C_;                   // 8 MB
  unsigned short* Kb      = Qb + (size_t)B_ * H_ * T_ * D_;         // 8 MB
  unsigned short* Vtb     = Kb + (size_t)B_ * H_ * T_ * D_;         // 8 MB
  unsigned short* yb      = Vtb + (size_t)B_ * H_ * T_ * D_;        // 8 MB

  hipMemsetAsync(sums, 0, 16, stream);
  abs_sum2<<<dim3(256, 2), 256, 0, stream>>>(w_qkv, w_proj, sums);
  tern_cvt<<<(4 * C_ * C_ + M_ * C_ / 4) / 256, 256, 0, stream>>>(w_qkv, w_proj, x,
                                                                  wqkv_b, wproj_b, xb,
                                                                  sums, ams);
  gemm_qkv<<<dim3(N3C / 128, M_ / 128), 256, 0, stream>>>(xb, wqkv_b, ams + 0,
                                                          cosp, sinp, Qb, Kb, Vtb);
  flash_mfma<<<512, 256, 0, stream>>>(Qb, Kb, Vtb, yb);
  gemm128<<<dim3(C_ / 128, M_ / 128), 256, 0, stream>>>(yb, wproj_b, ams + 1, out, C_, C_);
}

// Round 9
// 207.227 us; speedup vs baseline: 1.0959x; 1.0959x over previous
//
#include <hip/hip_runtime.h>
#include <hip/hip_bf16.h>

// Problem constants: B=2, T=2048, C=1024, H=16, D=64
#define B_ 2
#define T_ 2048
#define C_ 1024
#define H_ 16
#define D_ 64
#define M_ 4096
#define N3C 3072

using short8  = __attribute__((ext_vector_type(8))) short;
using floatx4 = __attribute__((ext_vector_type(4))) float;
typedef unsigned int u32;

__device__ __forceinline__ unsigned short f2b(float f) {
  __hip_bfloat16 h = __float2bfloat16(f);
  return *reinterpret_cast<unsigned short*>(&h);
}
__device__ __forceinline__ float b2f(unsigned short u) {
  union { unsigned int i; float f; } x; x.i = ((unsigned int)u) << 16; return x.f;
}
__device__ __forceinline__ u32 pk2(float a, float b) {   // packed bf16x2
  float2 t; t.x = a; t.y = b;
  __hip_bfloat162 p = __float22bfloat162_rn(t);
  return *reinterpret_cast<u32*>(&p);
}

// async global->LDS, 16B per lane; LDS dest = wave-uniform base + lane*16
__device__ __forceinline__ void gll16(const void* g, void* l) {
  __builtin_amdgcn_global_load_lds((const __attribute__((address_space(1))) u32*)g,
                                   (__attribute__((address_space(3))) u32*)l, 16, 0, 0);
}

// ---------------- ternarization ----------------

// both tensors in one launch; per-block LDS reduce -> 1 atomic/block
__global__ void abs_sum2(const float* __restrict__ wq, const float* __restrict__ wp,
                         double* __restrict__ sums) {
  __shared__ double red[4];
  const float* w = blockIdx.y ? wp : wq;
  const int n4 = blockIdx.y ? (C_ * C_ / 4) : (3 * C_ * C_ / 4);
  int stride = gridDim.x * blockDim.x;
  double s = 0.0;
  for (int i = blockIdx.x * blockDim.x + threadIdx.x; i < n4; i += stride) {
    float4 v = ((const float4*)w)[i];
    s += (double)fabsf(v.x) + (double)fabsf(v.y) + (double)fabsf(v.z) + (double)fabsf(v.w);
  }
  #pragma unroll
  for (int off = 32; off > 0; off >>= 1)
    s += __shfl_down(s, off, 64);
  if ((threadIdx.x & 63) == 0) red[threadIdx.x >> 6] = s;
  __syncthreads();
  if (threadIdx.x == 0) atomicAdd(sums + blockIdx.y, (red[0] + red[1]) + (red[2] + red[3]));
}

// ternarize both weight tensors (exact {-1,0,+1} bf16) + cvt x->bf16, one launch
__global__ void tern_cvt(const float* __restrict__ wq, const float* __restrict__ wp,
                         const float* __restrict__ x,
                         unsigned short* __restrict__ oq, unsigned short* __restrict__ op,
                         unsigned short* __restrict__ xb,
                         const double* __restrict__ sums, float* __restrict__ ams) {
  const int NQ = 3 * C_ * C_;
  const int NP = C_ * C_;
  int i = blockIdx.x * blockDim.x + threadIdx.x;
  float am0 = fmaxf((float)(sums[0] * (1.0 / NQ)), 1e-5f);
  float am1 = fmaxf((float)(sums[1] * (1.0 / NP)), 1e-5f);
  if (i == 0) { ams[0] = am0; ams[1] = am1; }
  if (i < NQ) {
    float thr = 0.7f * am0, v = wq[i];
    oq[i] = (v > thr) ? 0x3F80u : ((v < -thr) ? 0xBF80u : 0u);
  } else if (i < NQ + NP) {
    int j = i - NQ;
    float thr = 0.7f * am1, v = wp[j];
    op[j] = (v > thr) ? 0x3F80u : ((v < -thr) ? 0xBF80u : 0u);
  } else {
    int j = i - NQ - NP;                       // 0 .. M_*C_/4-1
    float4 v = ((const float4*)x)[j];
    ushort4 o; o.x = f2b(v.x); o.y = f2b(v.y); o.z = f2b(v.z); o.w = f2b(v.w);
    ((ushort4*)xb)[j] = o;
  }
}

// ---------------- QKV GEMM with fused RoPE/head-split/V-transpose epilogue ----
// 128x128 tile, BK=32, 256 threads, global_load_lds staging. Epilogue:
// q/k -> in-register RoPE (partners acc[r][c]/acc[r][c^2]) -> Qb/Kb [bh][t][d];
// v -> Vtb [bh][d][t] directly. Q pre-scaled by am*0.125*log2e.

__global__ __launch_bounds__(256) void gemm_qkv(const unsigned short* __restrict__ A,
                                                const unsigned short* __restrict__ W,
                                                const float* __restrict__ scale_ptr,
                                                const float* __restrict__ cosp,
                                                const float* __restrict__ sinp,
                                                unsigned short* __restrict__ Qb,
                                                unsigned short* __restrict__ Kb,
                                                unsigned short* __restrict__ Vtb) {
  const int K = C_;
  __shared__ __attribute__((aligned(16))) unsigned short As[128 * 32];
  __shared__ __attribute__((aligned(16))) unsigned short Ws[128 * 32];
  const int tid = threadIdx.x, lane = tid & 63, wv = tid >> 6;
  const int m = lane & 15, g = lane >> 4;
  const int m0 = blockIdx.y * 128, n0 = blockIdx.x * 128;
  const int wm = (wv >> 1) * 64, wn = (wv & 1) * 64;

  const int srow = wv * 16 + (lane >> 2);
  const int skoff = (lane & 3) * 8;
  const unsigned short* ga0 = A + (size_t)(m0 + srow) * K + skoff;
  const unsigned short* ga1 = A + (size_t)(m0 + 64 + srow) * K + skoff;
  const unsigned short* gw0 = W + (size_t)(n0 + srow) * K + skoff;
  const unsigned short* gw1 = W + (size_t)(n0 + 64 + srow) * K + skoff;
  unsigned short* la0 = As + (wv * 16) * 32;
  unsigned short* la1 = As + (64 + wv * 16) * 32;
  unsigned short* lw0 = Ws + (wv * 16) * 32;
  unsigned short* lw1 = Ws + (64 + wv * 16) * 32;

  floatx4 acc[4][4] = {};
  for (int kc = 0; kc < K; kc += 32) {
    __syncthreads();
    gll16(ga0, la0); gll16(ga1, la1); gll16(gw0, lw0); gll16(gw1, lw1);
    ga0 += 32; ga1 += 32; gw0 += 32; gw1 += 32;
    __syncthreads();
    short8 af[4], wf[4];
    #pragma unroll
    for (int r = 0; r < 4; r++)
      af[r] = *(const short8*)&As[(wm + r * 16 + m) * 32 + g * 8];
    #pragma unroll
    for (int c = 0; c < 4; c++)
      wf[c] = *(const short8*)&Ws[(wn + c * 16 + m) * 32 + g * 8];
    #pragma unroll
    for (int r = 0; r < 4; r++)
      #pragma unroll
      for (int c = 0; c < 4; c++)
        acc[r][c] = __builtin_amdgcn_mfma_f32_16x16x32_bf16(af[r], wf[c], acc[r][c], 0, 0, 0);
  }

  const float am = *scale_ptr;
  const int sect = n0 >> 10;            // 0=q, 1=k, 2=v (block-uniform)
  const int nloc = n0 & 1023;
  const int h = (nloc + wn) >> 6;       // head for this wave's 64-col half
  if (sect < 2) {
    unsigned short* dst = sect ? Kb : Qb;
    const float sc = sect ? am : am * 0.18033688011112042f;  // am * 0.125 * log2(e)
    #pragma unroll
    for (int r = 0; r < 4; r++)
      #pragma unroll
      for (int i = 0; i < 4; i++) {
        int row = m0 + wm + r * 16 + g * 4 + i;
        int t = row & (T_ - 1), b = row >> 11;
        size_t obase = ((size_t)(b * H_ + h) * T_ + t) * 64;
        #pragma unroll
        for (int c = 0; c < 4; c++) {
          int p = c * 16 + m;
          float cv = cosp[t * 64 + p], sv = sinp[t * 64 + p];
          float a = acc[r][c][i], pt = acc[r][c ^ 2][i];
          float val = (c < 2) ? (a * cv - pt * sv) : (a * cv + pt * sv);
          dst[obase + p] = f2b(val * sc);
        }
      }
  } else {
    #pragma unroll
    for (int r = 0; r < 4; r++)
      #pragma unroll
      for (int i = 0; i < 4; i++) {
        int row = m0 + wm + r * 16 + g * 4 + i;
        int t = row & (T_ - 1), b = row >> 11;
        size_t hbase = (size_t)(b * H_ + h) * 64 * T_;
        #pragma unroll
        for (int c = 0; c < 4; c++)
          Vtb[hbase + (size_t)(c * 16 + m) * T_ + t] = f2b(acc[r][c][i] * am);
      }
  }
}

// ---------------- proj GEMM: out[M,N] = (A @ W^T) * scale, fp32 out ----------
// 128x64 tile -> 512 blocks (2/CU, vs 256=1/CU at 128x128 which exposed every
// barrier drain). 4 waves as 2(M) x 2(N): wave = 64x32, acc[4][2].

__global__ __launch_bounds__(256) void gemm_proj(const unsigned short* __restrict__ A,
                                                 const unsigned short* __restrict__ W,
                                                 const float* __restrict__ scale_ptr,
                                                 float* __restrict__ Cout) {
  const int K = C_, N = C_;
  __shared__ __attribute__((aligned(16))) unsigned short As[128 * 32];
  __shared__ __attribute__((aligned(16))) unsigned short Ws[64 * 32];
  const int tid = threadIdx.x, lane = tid & 63, wv = tid >> 6;
  const int m = lane & 15, g = lane >> 4;
  const int m0 = blockIdx.y * 128, n0 = blockIdx.x * 64;
  const int wm = (wv >> 1) * 64, wn = (wv & 1) * 32;

  const int srow = wv * 16 + (lane >> 2);
  const int skoff = (lane & 3) * 8;
  const unsigned short* ga0 = A + (size_t)(m0 + srow) * K + skoff;
  const unsigned short* ga1 = A + (size_t)(m0 + 64 + srow) * K + skoff;
  const unsigned short* gw0 = W + (size_t)(n0 + srow) * K + skoff;
  unsigned short* la0 = As + (wv * 16) * 32;
  unsigned short* la1 = As + (64 + wv * 16) * 32;
  unsigned short* lw0 = Ws + (wv * 16) * 32;

  floatx4 acc[4][2] = {};
  for (int kc = 0; kc < K; kc += 32) {
    __syncthreads();
    gll16(ga0, la0); gll16(ga1, la1); gll16(gw0, lw0);
    ga0 += 32; ga1 += 32; gw0 += 32;
    __syncthreads();
    short8 af[4], wf[2];
    #pragma unroll
    for (int r = 0; r < 4; r++)
      af[r] = *(const short8*)&As[(wm + r * 16 + m) * 32 + g * 8];
    #pragma unroll
    for (int c = 0; c < 2; c++)
      wf[c] = *(const short8*)&Ws[(wn + c * 16 + m) * 32 + g * 8];
    #pragma unroll
    for (int r = 0; r < 4; r++)
      #pragma unroll
      for (int c = 0; c < 2; c++)
        acc[r][c] = __builtin_amdgcn_mfma_f32_16x16x32_bf16(af[r], wf[c], acc[r][c], 0, 0, 0);
  }

  const float scale = *scale_ptr;
  #pragma unroll
  for (int r = 0; r < 4; r++)
    #pragma unroll
    for (int c = 0; c < 2; c++)
      #pragma unroll
      for (int i = 0; i < 4; i++) {
        int row = m0 + wm + r * 16 + g * 4 + i;
        int col = n0 + wn + c * 16 + m;
        Cout[(size_t)row * N + col] = acc[r][c][i] * scale;
      }
}

// ---------------- MFMA flash attention, m=0 softmax, LDS-staged K/V ----------
// 1024 blocks, one 64-q strip each (32 strips x 32 bh), LPT order (long strips
// first) + XCD swizzle (4 bh per gid%8) -> ~4 blocks/CU with backfill balance.
// Wave owns 16 q. K/V double-buffered via global_load_lds, XOR-swizzled 16B
// chunks. S^T = K*Q^T; P packed via v_cvt_pk_bf16_f32, LDS round-trip;
// O += P*V; l via ones-MFMA (C-layout lands l(q=g*4+r) in reg r -> no shuffle
// reduction at all).

__global__ __launch_bounds__(256) void flash_mfma(const unsigned short* __restrict__ Qb,
                                                  const unsigned short* __restrict__ Kb,
                                                  const unsigned short* __restrict__ Vtb,
                                                  unsigned short* __restrict__ Y) {
  __shared__ __align__(16) unsigned short Ktile[2][64][64];   // [buf][t][d]
  __shared__ __align__(16) unsigned short Vtile[2][64][64];   // [buf][d][t]
  __shared__ __align__(16) unsigned short Plds[4][16][72];
  const int lane = threadIdx.x & 63;
  const int wv = threadIdx.x >> 6;
  const int m = lane & 15, g = lane >> 4;
  const int gid = blockIdx.x;
  const int xcd = gid & 7, j = gid >> 3;    // j: 0..127
  const int bh = xcd * 4 + (j & 3);
  const int s = 31 - (j >> 2);              // long strips dispatched first
  const int b = bh >> 4, h = bh & 15;
  const size_t hb = (size_t)bh * T_ * 64;
  const unsigned short* Kbh = Kb + hb;
  const unsigned short* Vbh = Vtb + hb;     // [64][T_]
  const int r8 = lane >> 3, cc8 = lane & 7;
  const int gcol = ((cc8 ^ r8) << 3);       // swizzled global chunk

  const int ntiles = s + 1;
  const int qbase = s * 64 + wv * 16;
  const int q_glob = qbase + m;

  const unsigned short* qp = Qb + hb + (size_t)(qbase + m) * 64 + g * 8;
  short8 qf0 = *(const short8*)qp;
  short8 qf1 = *(const short8*)(qp + 32);

  short8 ones;
  #pragma unroll
  for (int i = 0; i < 8; i++) ones[i] = (short)0x3F80;  // bf16 1.0

  floatx4 O[4] = {};
  floatx4 accl = {};

  #pragma unroll
  for (int cc = 0; cc < 2; cc++) {          // stage tile 0 -> buf 0
    int row = wv * 16 + cc * 8;
    gll16(Kbh + (size_t)(row + r8) * 64 + gcol, &Ktile[0][row][0]);
    gll16(Vbh + (size_t)(row + r8) * T_ + gcol, &Vtile[0][row][0]);
  }

  for (int kt = 0; kt < ntiles; kt++) {
    const int buf = kt & 1;
    const int kb = kt * 64;
    __syncthreads();                         // stage(kt) visible
    if (kt + 1 < ntiles) {                   // stream next tile
      const int kb2 = kb + 64;
      #pragma unroll
      for (int cc = 0; cc < 2; cc++) {
        int row = wv * 16 + cc * 8;
        gll16(Kbh + (size_t)(kb2 + row + r8) * 64 + gcol, &Ktile[1 - buf][row][0]);
        gll16(Vbh + (size_t)(row + r8) * T_ + kb2 + gcol, &Vtile[1 - buf][row][0]);
      }
    }
    // S^T = K * Q^T  (swizzled reads: G[r][c] = LDS[r][c ^ (r&7)])
    floatx4 S[4];
    #pragma unroll
    for (int mt = 0; mt < 4; mt++) {
      int row = mt * 16 + m;
      short8 kf0 = *(const short8*)&Ktile[buf][row][(g ^ (m & 7)) << 3];
      short8 kf1 = *(const short8*)&Ktile[buf][row][((g + 4) ^ (m & 7)) << 3];
      floatx4 sv = {};
      sv = __builtin_amdgcn_mfma_f32_16x16x32_bf16(kf0, qf0, sv, 0, 0, 0);
      sv = __builtin_amdgcn_mfma_f32_16x16x32_bf16(kf1, qf1, sv, 0, 0, 0);
      S[mt] = sv;
    }
    if (kt + 1 < ntiles) {                   // fully unmasked tile
      #pragma unroll
      for (int mt = 0; mt < 4; mt++) {
        uint2 w;
        w.x = pk2(exp2f(S[mt][0]), exp2f(S[mt][1]));
        w.y = pk2(exp2f(S[mt][2]), exp2f(S[mt][3]));
        *(uint2*)&Plds[wv][m][mt * 16 + g * 4] = w;
      }
    } else {                                 // diagonal tile: causal mask
      #pragma unroll
      for (int mt = 0; mt < 4; mt++) {
        float e[4];
        #pragma unroll
        for (int r = 0; r < 4; r++) {
          int kg = kb + mt * 16 + g * 4 + r;
          e[r] = (kg <= q_glob) ? exp2f(S[mt][r]) : 0.f;
        }
        uint2 w;
        w.x = pk2(e[0], e[1]);
        w.y = pk2(e[2], e[3]);
        *(uint2*)&Plds[wv][m][mt * 16 + g * 4] = w;
      }
    }
    short8 pa0 = *(const short8*)&Plds[wv][m][g * 8];
    short8 pa1 = *(const short8*)&Plds[wv][m][32 + g * 8];
    #pragma unroll
    for (int nt = 0; nt < 4; nt++) {
      int row = nt * 16 + m;
      short8 v0 = *(const short8*)&Vtile[buf][row][(g ^ (m & 7)) << 3];
      short8 v1 = *(const short8*)&Vtile[buf][row][((g + 4) ^ (m & 7)) << 3];
      O[nt] = __builtin_amdgcn_mfma_f32_16x16x32_bf16(pa0, v0, O[nt], 0, 0, 0);
      O[nt] = __builtin_amdgcn_mfma_f32_16x16x32_bf16(pa1, v1, O[nt], 0, 0, 0);
    }
    accl = __builtin_amdgcn_mfma_f32_16x16x32_bf16(pa0, ones, accl, 0, 0, 0);
    accl = __builtin_amdgcn_mfma_f32_16x16x32_bf16(pa1, ones, accl, 0, 0, 0);
  }

  // accl[r] = l(q = qbase + g*4 + r) -- no cross-lane reduction needed
  float li[4];
  #pragma unroll
  for (int r = 0; r < 4; r++) li[r] = 1.0f / accl[r];
  #pragma unroll
  for (int nt = 0; nt < 4; nt++)
    #pragma unroll
    for (int r = 0; r < 4; r++) {
      int trow = qbase + g * 4 + r;
      int col = h * 64 + nt * 16 + m;
      Y[(size_t)(b * T_ + trow) * C_ + col] = f2b(O[nt][r] * li[r]);
    }
}

// ---------------- launch ----------------

extern "C" void kernel_launch(void* const* d_in, const int* in_sizes, int n_in,
                              void* d_out, int out_size, void* d_ws, size_t ws_size,
                              hipStream_t stream) {
  (void)in_sizes; (void)n_in; (void)out_size; (void)ws_size;
  const float* x      = (const float*)d_in[0];
  const float* cosp   = (const float*)d_in[1];
  const float* sinp   = (const float*)d_in[2];
  const float* w_qkv  = (const float*)d_in[3];
  const float* w_proj = (const float*)d_in[4];
  float* out = (float*)d_out;

  char* ws = (char*)d_ws;
  double* sums = (double*)ws;                       // 16 B
  float*  ams  = (float*)(ws + 16);                 // 8 B
  unsigned short* wqkv_b  = (unsigned short*)(ws + 256);            // 6 MB
  unsigned short* wproj_b = wqkv_b + (size_t)N3C * C_;              // 2 MB
  unsigned short* xb      = wproj_b + (size_t)C_ * C_;              // 8 MB
  unsigned short* Qb      = xb + (size_t)M_ * C_;                   // 8 MB
  unsigned short* Kb      = Qb + (size_t)B_ * H_ * T_ * D_;         // 8 MB
  unsigned short* Vtb     = Kb + (size_t)B_ * H_ * T_ * D_;         // 8 MB
  unsigned short* yb      = Vtb + (size_t)B_ * H_ * T_ * D_;        // 8 MB

  hipMemsetAsync(sums, 0, 16, stream);
  abs_sum2<<<dim3(256, 2), 256, 0, stream>>>(w_qkv, w_proj, sums);
  tern_cvt<<<(4 * C_ * C_ + M_ * C_ / 4) / 256, 256, 0, stream>>>(w_qkv, w_proj, x,
                                                                  wqkv_b, wproj_b, xb,
                                                                  sums, ams);
  gemm_qkv<<<dim3(N3C / 128, M_ / 128), 256, 0, stream>>>(xb, wqkv_b, ams + 0,
                                                          cosp, sinp, Qb, Kb, Vtb);
  flash_mfma<<<1024, 256, 0, stream>>>(Qb, Kb, Vtb, yb);
  gemm_proj<<<dim3(C_ / 64, M_ / 128), 256, 0, stream>>>(yb, wproj_b, ams + 1, out);
}